// Round 8
// baseline (730.081 us; speedup 1.0000x reference)
//
#include <hip/hip_runtime.h>

#define DD 64
#define NBX 1024   // max coarse buckets (128 nodes each -> Nn <= 131072)

typedef __attribute__((ext_vector_type(8))) short bfrag;
typedef __attribute__((ext_vector_type(4))) float ffrag;

static __device__ __forceinline__ short f2bf(float f) {
  union { float f; unsigned u; } v; v.f = f;
  unsigned r = v.u + 0x7fff + ((v.u >> 16) & 1);  // RNE
  return (short)(r >> 16);
}
static __device__ __forceinline__ float bf2f(unsigned short u) {
  union { unsigned u; float f; } v; v.u = ((unsigned)u) << 16; return v.f;
}

// ================== coarse (128-node bucket) CSR build ==================

__global__ void chist_kernel(const int* __restrict__ dst, int* __restrict__ ccnt,
                             int E, int NB) {
  __shared__ int ch[NBX];
  for (int i = threadIdx.x; i < NBX; i += 256) ch[i] = 0;
  __syncthreads();
  int ebase = blockIdx.x * 4096;
#pragma unroll
  for (int j = 0; j < 16; ++j) {
    int e = ebase + j * 256 + threadIdx.x;
    if (e < E) atomicAdd(&ch[dst[e] >> 7], 1);
  }
  __syncthreads();
  for (int b = threadIdx.x; b < NB; b += 256) {
    int c = ch[b];
    if (c) atomicAdd(&ccnt[b], c);
  }
}

// single block; scans up to 1024 bucket counts (4 per thread)
__global__ void cscan_kernel(const int* __restrict__ ccnt, int* __restrict__ cbase,
                             int* __restrict__ ccursor, int NB) {
  __shared__ int wtot[4];
  int t = threadIdx.x;
  int v[4];
  int s = 0;
#pragma unroll
  for (int j = 0; j < 4; ++j) {
    int idx = t * 4 + j;
    v[j] = (idx < NB) ? ccnt[idx] : 0;
    s += v[j];
  }
  int lane = t & 63, w = t >> 6;
  int ps = s;
#pragma unroll
  for (int off = 1; off < 64; off <<= 1) {
    int tmp = __shfl_up(ps, off);
    if (lane >= off) ps += tmp;
  }
  if (lane == 63) wtot[w] = ps;
  __syncthreads();
  int wbase = 0;
  for (int k = 0; k < w; ++k) wbase += wtot[k];
  int excl = wbase + ps - s;
  int run = excl;
#pragma unroll
  for (int j = 0; j < 4; ++j) {
    int idx = t * 4 + j;
    if (idx < NB) { cbase[idx] = run; ccursor[idx] = run; }
    run += v[j];
  }
  if (t == 255) cbase[NB] = excl + s;  // total
}

// coarse scatter: pack (src<<7)|(dst&127) into pairb, grouped by bucket dst>>7
__global__ void cscatter_kernel(const int* __restrict__ src, const int* __restrict__ dst,
                                int* __restrict__ ccursor, unsigned* __restrict__ pairb,
                                int E, int NB) {
  __shared__ int bh[NBX], bbase[NBX], brank[NBX];
  for (int i = threadIdx.x; i < NBX; i += 256) { bh[i] = 0; brank[i] = 0; }
  __syncthreads();
  int ebase = blockIdx.x * 4096;
  int se[16], de[16];
#pragma unroll
  for (int j = 0; j < 16; ++j) {
    int e = ebase + j * 256 + threadIdx.x;
    if (e < E) {
      se[j] = src[e];
      de[j] = dst[e];
      atomicAdd(&bh[de[j] >> 7], 1);
    } else {
      se[j] = -1; de[j] = 0;
    }
  }
  __syncthreads();
  for (int b = threadIdx.x; b < NB; b += 256) {
    int c = bh[b];
    bbase[b] = c ? atomicAdd(&ccursor[b], c) : 0;
  }
  __syncthreads();
#pragma unroll
  for (int j = 0; j < 16; ++j) {
    if (se[j] >= 0) {
      int b = de[j] >> 7;
      int r = atomicAdd(&brank[b], 1);
      pairb[bbase[b] + r] = ((unsigned)se[j] << 7) | (unsigned)(de[j] & 127);
    }
  }
}

// ================== pre-scale h by norm into bf16 ==================

__global__ void hconv_kernel(const float* __restrict__ ue, const float* __restrict__ ie,
                             const float* __restrict__ norm,
                             unsigned short* __restrict__ hsc, int Nn, int NU) {
  int tid = blockIdx.x * blockDim.x + threadIdx.x;
  if (tid >= Nn * 16) return;
  int row = tid >> 4;
  int q = tid & 15;
  const float* hr = (row < NU) ? ue + (size_t)row * DD : ie + (size_t)(row - NU) * DD;
  float nr = norm[row];
  float4 hv = reinterpret_cast<const float4*>(hr)[q];
  unsigned u0 = (unsigned short)f2bf(nr * hv.x);
  unsigned u1 = (unsigned short)f2bf(nr * hv.y);
  unsigned u2 = (unsigned short)f2bf(nr * hv.z);
  unsigned u3 = (unsigned short)f2bf(nr * hv.w);
  uint2 pk;
  pk.x = u0 | (u1 << 16);
  pk.y = u2 | (u3 << 16);
  *reinterpret_cast<uint2*>(hsc + (size_t)row * DD + q * 4) = pk;
}

// ========== bucket-fused: stream pairb -> LDS g tile -> MFMA -> out ==========
// Block = one 128-node bucket. Gather uses the R5-proven shape: wave-uniform
// scalar edge loads, full-wave 128B row loads, 8 independent loads in flight.
// Accumulate via LDS float atomics (row-per-node, lane-per-feature: 2-way banks).
__launch_bounds__(256)
__global__ void bucket_fused_kernel(const unsigned short* __restrict__ hsc,
                                    const float* __restrict__ norm,
                                    const float* __restrict__ W1,
                                    const float* __restrict__ W2,
                                    const unsigned* __restrict__ pairb,
                                    const int* __restrict__ cbase,
                                    float* __restrict__ out, int Nn) {
  __shared__ float gt[128][68];
  int tid = threadIdx.x;
  int lane = tid & 63;
  int w = tid >> 6;
  int b = blockIdx.x;

  float* gflat = &gt[0][0];
  for (int i = tid; i < 128 * 68; i += 256) gflat[i] = 0.f;
  __syncthreads();

  // ---- phase 1: stream this bucket's edges ----
  int cbeg = cbase[b], cend = cbase[b + 1];
  int tot = cend - cbeg;
  int chunk = (tot + 3) >> 2;
  int pbeg = cbeg + w * chunk;
  int pend = pbeg + chunk;
  if (pend > cend) pend = cend;

  int p = pbeg;
  for (; p + 8 <= pend; p += 8) {
    unsigned v0 = pairb[p + 0], v1 = pairb[p + 1];
    unsigned v2 = pairb[p + 2], v3 = pairb[p + 3];
    unsigned v4 = pairb[p + 4], v5 = pairb[p + 5];
    unsigned v6 = pairb[p + 6], v7 = pairb[p + 7];
    float f0 = bf2f(hsc[(size_t)(v0 >> 7) * DD + lane]);
    float f1 = bf2f(hsc[(size_t)(v1 >> 7) * DD + lane]);
    float f2 = bf2f(hsc[(size_t)(v2 >> 7) * DD + lane]);
    float f3 = bf2f(hsc[(size_t)(v3 >> 7) * DD + lane]);
    float f4 = bf2f(hsc[(size_t)(v4 >> 7) * DD + lane]);
    float f5 = bf2f(hsc[(size_t)(v5 >> 7) * DD + lane]);
    float f6 = bf2f(hsc[(size_t)(v6 >> 7) * DD + lane]);
    float f7 = bf2f(hsc[(size_t)(v7 >> 7) * DD + lane]);
    atomicAdd(&gt[v0 & 127u][lane], f0);
    atomicAdd(&gt[v1 & 127u][lane], f1);
    atomicAdd(&gt[v2 & 127u][lane], f2);
    atomicAdd(&gt[v3 & 127u][lane], f3);
    atomicAdd(&gt[v4 & 127u][lane], f4);
    atomicAdd(&gt[v5 & 127u][lane], f5);
    atomicAdd(&gt[v6 & 127u][lane], f6);
    atomicAdd(&gt[v7 & 127u][lane], f7);
  }
  for (; p < pend; ++p) {
    unsigned v = pairb[p];
    atomicAdd(&gt[v & 127u][lane], bf2f(hsc[(size_t)(v >> 7) * DD + lane]));
  }
  __syncthreads();

  // ---- phase 2: MFMA transform, 2 16-node tiles per wave ----
  int l15 = lane & 15;
  int lg  = lane >> 4;

  bfrag w1f[2][4], w2f[2][4];
#pragma unroll
  for (int jt = 0; jt < 4; ++jt) {
    int wrow = jt * 16 + l15;
#pragma unroll
    for (int ks = 0; ks < 2; ++ks) {
      int kb = ks * 32 + lg * 8;
      const float* p1 = W1 + wrow * DD + kb;
      const float* p2 = W2 + wrow * DD + kb;
#pragma unroll
      for (int j = 0; j < 8; ++j) {
        w1f[ks][jt][j] = f2bf(p1[j]);
        w2f[ks][jt][j] = f2bf(p2[j]);
      }
    }
  }

#pragma unroll
  for (int tt = 0; tt < 2; ++tt) {
    int t = w * 2 + tt;
    int rowbase = b * 128 + t * 16;
    if (rowbase >= Nn) break;
    int node = rowbase + l15;
    int nc = (node < Nn) ? node : (Nn - 1);
    float nd = norm[nc];
    float rnd = 1.0f / nd;

    ffrag acc[4];
#pragma unroll
    for (int jt = 0; jt < 4; ++jt) acc[jt] = (ffrag){0.f, 0.f, 0.f, 0.f};

#pragma unroll
    for (int ks = 0; ks < 2; ++ks) {
      int kb = ks * 32 + lg * 8;
      float4 g0 = *reinterpret_cast<const float4*>(&gt[t * 16 + l15][kb]);
      float4 g1 = *reinterpret_cast<const float4*>(&gt[t * 16 + l15][kb + 4]);
      bfrag hb = *reinterpret_cast<const bfrag*>(hsc + (size_t)nc * DD + kb);
      float gv[8] = {g0.x, g0.y, g0.z, g0.w, g1.x, g1.y, g1.z, g1.w};
      bfrag xf, yf;
#pragma unroll
      for (int j = 0; j < 8; ++j) {
        float hj = bf2f((unsigned short)hb[j]);     // = nd * h_j
        xf[j] = f2bf(fmaf(nd, gv[j], hj * rnd));    // nd*g + h
        yf[j] = f2bf(gv[j] * hj);                   // nd*(g.*h)
      }
#pragma unroll
      for (int jt = 0; jt < 4; ++jt) {
        acc[jt] = __builtin_amdgcn_mfma_f32_16x16x32_bf16(xf, w1f[ks][jt], acc[jt], 0, 0, 0);
        acc[jt] = __builtin_amdgcn_mfma_f32_16x16x32_bf16(yf, w2f[ks][jt], acc[jt], 0, 0, 0);
      }
    }

    float v[4][4];
    float ss[4];
#pragma unroll
    for (int r = 0; r < 4; ++r) {
      float s = 0.f;
#pragma unroll
      for (int jt = 0; jt < 4; ++jt) {
        float m = acc[jt][r];
        float tt2 = (m >= 0.f) ? m : 0.2f * m;
        v[r][jt] = tt2;
        s = fmaf(tt2, tt2, s);
      }
#pragma unroll
      for (int off = 1; off < 16; off <<= 1) s += __shfl_xor(s, off);
      ss[r] = s;
    }
#pragma unroll
    for (int r = 0; r < 4; ++r) {
      int orow = rowbase + lg * 4 + r;
      if (orow < Nn) {
        float inv = 1.0f / fmaxf(sqrtf(ss[r]), 1e-12f);
#pragma unroll
        for (int jt = 0; jt < 4; ++jt)
          out[(size_t)orow * DD + jt * 16 + l15] = v[r][jt] * inv;
      }
    }
  }
}

// =====================  fallback CSR path (round-4, proven)  =====================

__global__ void hist_kernel(const int* __restrict__ dst, int* __restrict__ cnt, int E) {
  int e = blockIdx.x * blockDim.x + threadIdx.x;
  if (e < E) atomicAdd(&cnt[dst[e]], 1);
}

__global__ void scanA_kernel(const int* __restrict__ cnt, int* __restrict__ offs,
                             int* __restrict__ bsum, int Nn) {
  __shared__ int wsum[4];
  int base = blockIdx.x * 4096 + threadIdx.x * 16;
  int v[16];
  int s = 0;
#pragma unroll
  for (int i = 0; i < 16; ++i) {
    int idx = base + i;
    v[i] = (idx < Nn) ? cnt[idx] : 0;
    s += v[i];
  }
  int lane = threadIdx.x & 63, w = threadIdx.x >> 6;
  int ps = s;
#pragma unroll
  for (int off = 1; off < 64; off <<= 1) {
    int t = __shfl_up(ps, off);
    if (lane >= off) ps += t;
  }
  if (lane == 63) wsum[w] = ps;
  __syncthreads();
  int wbase = 0;
  for (int i = 0; i < w; ++i) wbase += wsum[i];
  int texcl = wbase + ps - s;
  int run = texcl;
#pragma unroll
  for (int i = 0; i < 16; ++i) {
    int idx = base + i;
    if (idx < Nn) offs[idx] = run;
    run += v[i];
  }
  if (threadIdx.x == blockDim.x - 1) bsum[blockIdx.x] = texcl + s;
}

__global__ void scanB_kernel(int* __restrict__ bsum, int nb) {
  if (threadIdx.x == 0 && blockIdx.x == 0) {
    int run = 0;
    for (int i = 0; i < nb; ++i) { int t = bsum[i]; bsum[i] = run; run += t; }
  }
}

__global__ void scanC_kernel(int* __restrict__ offs, int* __restrict__ cursor,
                             const int* __restrict__ bsum, int Nn) {
  int i = blockIdx.x * blockDim.x + threadIdx.x;
  if (i < Nn) {
    int v = offs[i] + bsum[i >> 12];
    offs[i] = v;
    cursor[i] = v;
  }
}

__global__ void bucket_kernel(const int* __restrict__ src, const int* __restrict__ dst,
                              int* __restrict__ cursor, int* __restrict__ ebuf, int E) {
  int e = blockIdx.x * blockDim.x + threadIdx.x;
  if (e < E) {
    int d = dst[e];
    int p = atomicAdd(&cursor[d], 1);
    ebuf[p] = src[e];
  }
}

__launch_bounds__(256)
__global__ void gather_g_kernel(const float* __restrict__ ue,
                                const float* __restrict__ ie,
                                const float* __restrict__ norm,
                                const int* __restrict__ offs,
                                const int* __restrict__ cnt,
                                const int* __restrict__ ebuf,
                                float* __restrict__ g,
                                int Nn, int NU) {
  int lane = threadIdx.x & 63;
  int wid = blockIdx.x * (blockDim.x >> 6) + (threadIdx.x >> 6);
  int d = __builtin_amdgcn_readfirstlane(wid);
  if (d >= Nn) return;
  int beg = __builtin_amdgcn_readfirstlane(offs[d]);
  int num = __builtin_amdgcn_readfirstlane(cnt[d]);
  float a0 = 0.f, a1 = 0.f, a2 = 0.f, a3 = 0.f;
  int i = 0;
  for (; i + 4 <= num; i += 4) {
    int s0 = ebuf[beg + i + 0];
    int s1 = ebuf[beg + i + 1];
    int s2 = ebuf[beg + i + 2];
    int s3 = ebuf[beg + i + 3];
    float w0 = norm[s0], w1 = norm[s1], w2 = norm[s2], w3 = norm[s3];
    const float* r0 = (s0 < NU) ? ue + (size_t)s0 * DD : ie + (size_t)(s0 - NU) * DD;
    const float* r1 = (s1 < NU) ? ue + (size_t)s1 * DD : ie + (size_t)(s1 - NU) * DD;
    const float* r2 = (s2 < NU) ? ue + (size_t)s2 * DD : ie + (size_t)(s2 - NU) * DD;
    const float* r3 = (s3 < NU) ? ue + (size_t)s3 * DD : ie + (size_t)(s3 - NU) * DD;
    a0 = fmaf(w0, r0[lane], a0);
    a1 = fmaf(w1, r1[lane], a1);
    a2 = fmaf(w2, r2[lane], a2);
    a3 = fmaf(w3, r3[lane], a3);
  }
  for (; i < num; ++i) {
    int s0 = ebuf[beg + i];
    float w0 = norm[s0];
    const float* r0 = (s0 < NU) ? ue + (size_t)s0 * DD : ie + (size_t)(s0 - NU) * DD;
    a0 = fmaf(w0, r0[lane], a0);
  }
  g[(size_t)d * DD + lane] = (a0 + a1) + (a2 + a3);
}

__launch_bounds__(256)
__global__ void node_mfma_kernel(const float* __restrict__ ue,
                                 const float* __restrict__ ie,
                                 const float* __restrict__ norm,
                                 const float* __restrict__ W1,
                                 const float* __restrict__ W2,
                                 const float* __restrict__ g,
                                 float* __restrict__ out,
                                 int Nn, int NU) {
  int lane = threadIdx.x & 63;
  int l15 = lane & 15;
  int lg  = lane >> 4;
  int tile = blockIdx.x * 4 + (threadIdx.x >> 6);

  bfrag w1f[2][4], w2f[2][4];
#pragma unroll
  for (int jt = 0; jt < 4; ++jt) {
    int wrow = jt * 16 + l15;
#pragma unroll
    for (int ks = 0; ks < 2; ++ks) {
      int kb = ks * 32 + lg * 8;
      const float* p1 = W1 + wrow * DD + kb;
      const float* p2 = W2 + wrow * DD + kb;
#pragma unroll
      for (int j = 0; j < 8; ++j) {
        w1f[ks][jt][j] = f2bf(p1[j]);
        w2f[ks][jt][j] = f2bf(p2[j]);
      }
    }
  }

  if (tile * 16 >= Nn) return;
  int node = tile * 16 + l15;
  int nclamp = (node < Nn) ? node : (Nn - 1);
  const float* hrow = (nclamp < NU) ? ue + (size_t)nclamp * DD
                                    : ie + (size_t)(nclamp - NU) * DD;
  const float* grow = g + (size_t)nclamp * DD;
  float nd = norm[nclamp];

  ffrag acc[4];
#pragma unroll
  for (int jt = 0; jt < 4; ++jt) acc[jt] = (ffrag){0.f, 0.f, 0.f, 0.f};

#pragma unroll
  for (int ks = 0; ks < 2; ++ks) {
    int kb = ks * 32 + lg * 8;
    bfrag xf, yf;
#pragma unroll
    for (int j = 0; j < 8; ++j) {
      float gv = grow[kb + j];
      float hv = hrow[kb + j];
      xf[j] = f2bf(fmaf(nd, gv, hv));
      yf[j] = f2bf(nd * gv * hv);
    }
#pragma unroll
    for (int jt = 0; jt < 4; ++jt) {
      acc[jt] = __builtin_amdgcn_mfma_f32_16x16x32_bf16(xf, w1f[ks][jt], acc[jt], 0, 0, 0);
      acc[jt] = __builtin_amdgcn_mfma_f32_16x16x32_bf16(yf, w2f[ks][jt], acc[jt], 0, 0, 0);
    }
  }

  float v[4][4];
  float ss[4];
#pragma unroll
  for (int r = 0; r < 4; ++r) {
    float s = 0.f;
#pragma unroll
    for (int jt = 0; jt < 4; ++jt) {
      float m = acc[jt][r];
      float t = (m >= 0.f) ? m : 0.2f * m;
      v[r][jt] = t;
      s = fmaf(t, t, s);
    }
#pragma unroll
    for (int off = 1; off < 16; off <<= 1) s += __shfl_xor(s, off);
    ss[r] = s;
  }
#pragma unroll
  for (int r = 0; r < 4; ++r) {
    int orow = tile * 16 + lg * 4 + r;
    if (orow < Nn) {
      float inv = 1.0f / fmaxf(sqrtf(ss[r]), 1e-12f);
#pragma unroll
      for (int jt = 0; jt < 4; ++jt)
        out[(size_t)orow * DD + jt * 16 + l15] = v[r][jt] * inv;
    }
  }
}

// =====================  launch  =====================

extern "C" void kernel_launch(void* const* d_in, const int* in_sizes, int n_in,
                              void* d_out, int out_size, void* d_ws, size_t ws_size,
                              hipStream_t stream) {
  const float* ue   = (const float*)d_in[0];
  const float* ie   = (const float*)d_in[1];
  const float* norm = (const float*)d_in[2];
  const int*   src  = (const int*)d_in[3];
  const int*   dst  = (const int*)d_in[4];
  const float* W1   = (const float*)d_in[5];
  const float* W2   = (const float*)d_in[6];
  float* out = (float*)d_out;

  int NU = in_sizes[0] / DD;
  int Nn = in_sizes[2];
  int E  = in_sizes[3];

  int NB = (Nn + 127) >> 7;   // 128-node buckets

  // fast-path ws: ctrl(1024+1025+1024 -> 3080) + pairb(E) + hsc(Nn*32 ints) + pad
  size_t fast_ints = 3080 + (size_t)E + (size_t)Nn * 32 + 8;
  size_t fast_bytes = fast_ints * sizeof(int);

  size_t csr_ints = (size_t)3 * Nn + 64 + (size_t)E;
  size_t csr_bytes = csr_ints * sizeof(int);

  if (NB <= NBX && ws_size >= fast_bytes) {
    int* ccnt    = (int*)d_ws;            // 1024
    int* cbase   = ccnt + 1024;           // 1025
    int* ccursor = cbase + 1025;          // 1024  (3073, pad to 3080)
    unsigned* pairb = (unsigned*)(ccnt + 3080);
    unsigned short* hsc = (unsigned short*)(pairb + E);

    hipMemsetAsync(ccnt, 0, 1024 * sizeof(int), stream);

    int EB = (E + 4095) / 4096;
    chist_kernel<<<EB, 256, 0, stream>>>(dst, ccnt, E, NB);
    cscan_kernel<<<1, 256, 0, stream>>>(ccnt, cbase, ccursor, NB);
    cscatter_kernel<<<EB, 256, 0, stream>>>(src, dst, ccursor, pairb, E, NB);
    hconv_kernel<<<(Nn * 16 + 255) / 256, 256, 0, stream>>>(ue, ie, norm, hsc, Nn, NU);
    bucket_fused_kernel<<<NB, 256, 0, stream>>>(hsc, norm, W1, W2, pairb, cbase,
                                                out, Nn);
  } else if (ws_size >= csr_bytes) {
    int* cnt    = (int*)d_ws;
    int* offs   = cnt + Nn;
    int* cursor = offs + Nn;
    int* bsum   = cursor + Nn;
    int* ebuf   = bsum + 64;
    size_t g_bytes = (size_t)Nn * DD * sizeof(float);
    float* g = (ws_size >= csr_bytes + g_bytes) ? (float*)(ebuf + E) : out;

    hipMemsetAsync(cnt, 0, (size_t)Nn * sizeof(int), stream);
    int eblk = (E + 255) / 256;
    hist_kernel<<<eblk, 256, 0, stream>>>(dst, cnt, E);
    int nblkA = (Nn + 4095) / 4096;
    scanA_kernel<<<nblkA, 256, 0, stream>>>(cnt, offs, bsum, Nn);
    scanB_kernel<<<1, 64, 0, stream>>>(bsum, nblkA);
    scanC_kernel<<<(Nn + 255) / 256, 256, 0, stream>>>(offs, cursor, bsum, Nn);
    bucket_kernel<<<eblk, 256, 0, stream>>>(src, dst, cursor, ebuf, E);
    gather_g_kernel<<<(Nn + 3) / 4, 256, 0, stream>>>(ue, ie, norm, offs, cnt, ebuf,
                                                      g, Nn, NU);
    int ntiles = (Nn + 15) / 16;
    node_mfma_kernel<<<(ntiles + 3) / 4, 256, 0, stream>>>(ue, ie, norm, W1, W2, g, out,
                                                           Nn, NU);
  }
}

// Round 9
// 252.381 us; speedup vs baseline: 2.8928x; 2.8928x over previous
//
#include <hip/hip_runtime.h>

#define DD 64

typedef __attribute__((ext_vector_type(8))) short bfrag;
typedef __attribute__((ext_vector_type(4))) float ffrag;

static __device__ __forceinline__ short f2bf(float f) {
  union { float f; unsigned u; } v; v.f = f;
  unsigned r = v.u + 0x7fff + ((v.u >> 16) & 1);  // RNE
  return (short)(r >> 16);
}
static __device__ __forceinline__ float bf2f(unsigned short u) {
  union { unsigned u; float f; } v; v.u = ((unsigned)u) << 16; return v.f;
}

// ================== two-level CSR build (coarse 256-node buckets) ==================

__global__ void chist_kernel(const int* __restrict__ dst, int* __restrict__ ccnt,
                             int E, int NB) {
  __shared__ int ch[512];
  for (int i = threadIdx.x; i < 512; i += 256) ch[i] = 0;
  __syncthreads();
  int ebase = blockIdx.x * 4096;
#pragma unroll
  for (int j = 0; j < 16; ++j) {
    int e = ebase + j * 256 + threadIdx.x;
    if (e < E) atomicAdd(&ch[dst[e] >> 8], 1);
  }
  __syncthreads();
  for (int b = threadIdx.x; b < NB; b += 256) {
    int c = ch[b];
    if (c) atomicAdd(&ccnt[b], c);
  }
}

__global__ void cscan_kernel(const int* __restrict__ ccnt, int* __restrict__ cbase,
                             int* __restrict__ ccursor, int NB) {
  __shared__ int wtot[4];
  int t = threadIdx.x;
  int i0 = t * 2, i1 = t * 2 + 1;
  int v0 = (i0 < NB) ? ccnt[i0] : 0;
  int v1 = (i1 < NB) ? ccnt[i1] : 0;
  int s = v0 + v1;
  int lane = t & 63, w = t >> 6;
  int ps = s;
#pragma unroll
  for (int off = 1; off < 64; off <<= 1) {
    int tmp = __shfl_up(ps, off);
    if (lane >= off) ps += tmp;
  }
  if (lane == 63) wtot[w] = ps;
  __syncthreads();
  int wbase = 0;
  for (int k = 0; k < w; ++k) wbase += wtot[k];
  int excl = wbase + ps - s;
  if (i0 < NB) { cbase[i0] = excl;      ccursor[i0] = excl; }
  if (i1 < NB) { cbase[i1] = excl + v0; ccursor[i1] = excl + v0; }
  if (t == 0) {
    int tot = 0;
    for (int k = 0; k < 4; ++k) tot += wtot[k];
    cbase[NB] = tot;
  }
}

__global__ void cscatter_kernel(const int* __restrict__ src, const int* __restrict__ dst,
                                int* __restrict__ ccursor, unsigned* __restrict__ pairb,
                                int E, int NB) {
  __shared__ int bh[512], bbase[512], brank[512];
  for (int i = threadIdx.x; i < 512; i += 256) { bh[i] = 0; brank[i] = 0; }
  __syncthreads();
  int ebase = blockIdx.x * 4096;
  int se[16], de[16];
#pragma unroll
  for (int j = 0; j < 16; ++j) {
    int e = ebase + j * 256 + threadIdx.x;
    if (e < E) {
      se[j] = src[e];
      de[j] = dst[e];
      atomicAdd(&bh[de[j] >> 8], 1);
    } else {
      se[j] = -1; de[j] = 0;
    }
  }
  __syncthreads();
  for (int b = threadIdx.x; b < NB; b += 256) {
    int c = bh[b];
    bbase[b] = c ? atomicAdd(&ccursor[b], c) : 0;
  }
  __syncthreads();
#pragma unroll
  for (int j = 0; j < 16; ++j) {
    if (se[j] >= 0) {
      int b = de[j] >> 8;
      int r = atomicAdd(&brank[b], 1);
      pairb[bbase[b] + r] = ((unsigned)se[j] << 8) | (unsigned)(de[j] & 255);
    }
  }
}

__global__ void fine_kernel(const unsigned* __restrict__ pairb,
                            const int* __restrict__ cbase,
                            int* __restrict__ offs, int* __restrict__ cnt,
                            int* __restrict__ ebuf, int Nn) {
  __shared__ int fh[256], fcur[256];
  __shared__ int wtot[4];
  int t = threadIdx.x, b = blockIdx.x;
  int nb0 = b << 8;
  int cbeg = cbase[b], cend = cbase[b + 1];
  fh[t] = 0;
  __syncthreads();
  for (int p = cbeg + t; p < cend; p += 256) atomicAdd(&fh[pairb[p] & 255u], 1);
  __syncthreads();
  int val = fh[t];
  int lane = t & 63, w = t >> 6;
  int ps = val;
#pragma unroll
  for (int off = 1; off < 64; off <<= 1) {
    int tmp = __shfl_up(ps, off);
    if (lane >= off) ps += tmp;
  }
  if (lane == 63) wtot[w] = ps;
  __syncthreads();
  int wbase = 0;
  for (int k = 0; k < w; ++k) wbase += wtot[k];
  int excl = wbase + ps - val;
  int node = nb0 + t;
  if (node < Nn) { offs[node] = cbeg + excl; cnt[node] = val; }
  fcur[t] = cbeg + excl;
  __syncthreads();
  for (int p = cbeg + t; p < cend; p += 256) {
    unsigned v = pairb[p];
    int pos = atomicAdd(&fcur[v & 255u], 1);
    ebuf[pos] = (int)(v >> 8);
  }
}

// ================== pre-scale h by norm into bf16 ==================

__global__ void hconv_kernel(const float* __restrict__ ue, const float* __restrict__ ie,
                             const float* __restrict__ norm,
                             unsigned short* __restrict__ hsc, int Nn, int NU) {
  int tid = blockIdx.x * blockDim.x + threadIdx.x;
  if (tid >= Nn * 16) return;
  int row = tid >> 4;
  int q = tid & 15;
  const float* hr = (row < NU) ? ue + (size_t)row * DD : ie + (size_t)(row - NU) * DD;
  float nr = norm[row];
  float4 hv = reinterpret_cast<const float4*>(hr)[q];
  unsigned u0 = (unsigned short)f2bf(nr * hv.x);
  unsigned u1 = (unsigned short)f2bf(nr * hv.y);
  unsigned u2 = (unsigned short)f2bf(nr * hv.z);
  unsigned u3 = (unsigned short)f2bf(nr * hv.w);
  uint2 pk;
  pk.x = u0 | (u1 << 16);
  pk.y = u2 | (u3 << 16);
  *reinterpret_cast<uint2*>(hsc + (size_t)row * DD + q * 4) = pk;
}

// ========== tile-fused: R5-shape gather (wave/node, serial-4) + MFMA epilogue ==========
// Block = one 16-node tile (4 waves). Wave w gathers nodes w*4..w*4+3 serially,
// each with the proven R5 inner loop (wave-uniform scalar beg/num, 4-deep
// independent full-wave row loads). LDS tile then feeds the proven MFMA phase.
__launch_bounds__(256)
__global__ void tile_fused_kernel(const unsigned short* __restrict__ hsc,
                                  const float* __restrict__ norm,
                                  const float* __restrict__ W1,
                                  const float* __restrict__ W2,
                                  const int* __restrict__ offs,
                                  const int* __restrict__ cnt,
                                  const int* __restrict__ ebuf,
                                  float* __restrict__ out, int Nn) {
  __shared__ float gt[16][68];
  int lane = threadIdx.x & 63;
  int w = threadIdx.x >> 6;
  int tile = blockIdx.x;

  // ---- phase 1: gather 4 nodes per wave, serially (R5 inner loop) ----
#pragma unroll
  for (int q = 0; q < 4; ++q) {
    int n_local = w * 4 + q;
    int node = tile * 16 + n_local;
    float a0 = 0.f, a1 = 0.f, a2 = 0.f, a3 = 0.f;
    if (node < Nn) {
      int beg = __builtin_amdgcn_readfirstlane(offs[node]);
      int num = __builtin_amdgcn_readfirstlane(cnt[node]);
      int i = 0;
      for (; i + 4 <= num; i += 4) {
        int s0 = ebuf[beg + i + 0];
        int s1 = ebuf[beg + i + 1];
        int s2 = ebuf[beg + i + 2];
        int s3 = ebuf[beg + i + 3];
        a0 += bf2f(hsc[(size_t)s0 * DD + lane]);
        a1 += bf2f(hsc[(size_t)s1 * DD + lane]);
        a2 += bf2f(hsc[(size_t)s2 * DD + lane]);
        a3 += bf2f(hsc[(size_t)s3 * DD + lane]);
      }
      for (; i < num; ++i) a0 += bf2f(hsc[(size_t)ebuf[beg + i] * DD + lane]);
    }
    gt[n_local][lane] = (a0 + a1) + (a2 + a3);
  }
  __syncthreads();

  // ---- phase 2: MFMA transform (every wave full tile; wave w stores rows lg==w) ----
  int l15 = lane & 15;
  int lg  = lane >> 4;

  bfrag w1f[2][4], w2f[2][4];
#pragma unroll
  for (int jt = 0; jt < 4; ++jt) {
    int wrow = jt * 16 + l15;
#pragma unroll
    for (int ks = 0; ks < 2; ++ks) {
      int kb = ks * 32 + lg * 8;
      const float* p1 = W1 + wrow * DD + kb;
      const float* p2 = W2 + wrow * DD + kb;
#pragma unroll
      for (int j = 0; j < 8; ++j) {
        w1f[ks][jt][j] = f2bf(p1[j]);
        w2f[ks][jt][j] = f2bf(p2[j]);
      }
    }
  }

  int node2 = tile * 16 + l15;
  int nc2 = (node2 < Nn) ? node2 : (Nn - 1);
  float nd = norm[nc2];
  float rnd = 1.0f / nd;

  ffrag acc[4];
#pragma unroll
  for (int jt = 0; jt < 4; ++jt) acc[jt] = (ffrag){0.f, 0.f, 0.f, 0.f};

#pragma unroll
  for (int ks = 0; ks < 2; ++ks) {
    int kb = ks * 32 + lg * 8;
    float4 g0 = *reinterpret_cast<const float4*>(&gt[l15][kb]);
    float4 g1 = *reinterpret_cast<const float4*>(&gt[l15][kb + 4]);
    bfrag hb = *reinterpret_cast<const bfrag*>(hsc + (size_t)nc2 * DD + kb);
    float gv[8] = {g0.x, g0.y, g0.z, g0.w, g1.x, g1.y, g1.z, g1.w};
    bfrag xf, yf;
#pragma unroll
    for (int j = 0; j < 8; ++j) {
      float hj = bf2f((unsigned short)hb[j]);      // = nd * h_j
      xf[j] = f2bf(fmaf(nd, gv[j], hj * rnd));     // nd*g + h
      yf[j] = f2bf(gv[j] * hj);                    // nd*(g.*h)
    }
#pragma unroll
    for (int jt = 0; jt < 4; ++jt) {
      acc[jt] = __builtin_amdgcn_mfma_f32_16x16x32_bf16(xf, w1f[ks][jt], acc[jt], 0, 0, 0);
      acc[jt] = __builtin_amdgcn_mfma_f32_16x16x32_bf16(yf, w2f[ks][jt], acc[jt], 0, 0, 0);
    }
  }

  float v[4][4];
  float ss[4];
#pragma unroll
  for (int r = 0; r < 4; ++r) {
    float s = 0.f;
#pragma unroll
    for (int jt = 0; jt < 4; ++jt) {
      float m = acc[jt][r];
      float t = (m >= 0.f) ? m : 0.2f * m;
      v[r][jt] = t;
      s = fmaf(t, t, s);
    }
#pragma unroll
    for (int off = 1; off < 16; off <<= 1) s += __shfl_xor(s, off);
    ss[r] = s;
  }
#pragma unroll
  for (int r = 0; r < 4; ++r) {
    if (lg == w) {
      int orow = tile * 16 + w * 4 + r;
      if (orow < Nn) {
        float inv = 1.0f / fmaxf(sqrtf(ss[r]), 1e-12f);
#pragma unroll
        for (int jt = 0; jt < 4; ++jt)
          out[(size_t)orow * DD + jt * 16 + l15] = v[r][jt] * inv;
      }
    }
  }
}

// =====================  fallback CSR path (round-4, proven)  =====================

__global__ void hist_kernel(const int* __restrict__ dst, int* __restrict__ cnt, int E) {
  int e = blockIdx.x * blockDim.x + threadIdx.x;
  if (e < E) atomicAdd(&cnt[dst[e]], 1);
}

__global__ void scanA_kernel(const int* __restrict__ cnt, int* __restrict__ offs,
                             int* __restrict__ bsum, int Nn) {
  __shared__ int wsum[4];
  int base = blockIdx.x * 4096 + threadIdx.x * 16;
  int v[16];
  int s = 0;
#pragma unroll
  for (int i = 0; i < 16; ++i) {
    int idx = base + i;
    v[i] = (idx < Nn) ? cnt[idx] : 0;
    s += v[i];
  }
  int lane = threadIdx.x & 63, w = threadIdx.x >> 6;
  int ps = s;
#pragma unroll
  for (int off = 1; off < 64; off <<= 1) {
    int t = __shfl_up(ps, off);
    if (lane >= off) ps += t;
  }
  if (lane == 63) wsum[w] = ps;
  __syncthreads();
  int wbase = 0;
  for (int i = 0; i < w; ++i) wbase += wsum[i];
  int texcl = wbase + ps - s;
  int run = texcl;
#pragma unroll
  for (int i = 0; i < 16; ++i) {
    int idx = base + i;
    if (idx < Nn) offs[idx] = run;
    run += v[i];
  }
  if (threadIdx.x == blockDim.x - 1) bsum[blockIdx.x] = texcl + s;
}

__global__ void scanB_kernel(int* __restrict__ bsum, int nb) {
  if (threadIdx.x == 0 && blockIdx.x == 0) {
    int run = 0;
    for (int i = 0; i < nb; ++i) { int t = bsum[i]; bsum[i] = run; run += t; }
  }
}

__global__ void scanC_kernel(int* __restrict__ offs, int* __restrict__ cursor,
                             const int* __restrict__ bsum, int Nn) {
  int i = blockIdx.x * blockDim.x + threadIdx.x;
  if (i < Nn) {
    int v = offs[i] + bsum[i >> 12];
    offs[i] = v;
    cursor[i] = v;
  }
}

__global__ void bucket_kernel(const int* __restrict__ src, const int* __restrict__ dst,
                              int* __restrict__ cursor, int* __restrict__ ebuf, int E) {
  int e = blockIdx.x * blockDim.x + threadIdx.x;
  if (e < E) {
    int d = dst[e];
    int p = atomicAdd(&cursor[d], 1);
    ebuf[p] = src[e];
  }
}

__launch_bounds__(256)
__global__ void gather_g_kernel(const float* __restrict__ ue,
                                const float* __restrict__ ie,
                                const float* __restrict__ norm,
                                const int* __restrict__ offs,
                                const int* __restrict__ cnt,
                                const int* __restrict__ ebuf,
                                float* __restrict__ g,
                                int Nn, int NU) {
  int lane = threadIdx.x & 63;
  int wid = blockIdx.x * (blockDim.x >> 6) + (threadIdx.x >> 6);
  int d = __builtin_amdgcn_readfirstlane(wid);
  if (d >= Nn) return;
  int beg = __builtin_amdgcn_readfirstlane(offs[d]);
  int num = __builtin_amdgcn_readfirstlane(cnt[d]);
  float a0 = 0.f, a1 = 0.f, a2 = 0.f, a3 = 0.f;
  int i = 0;
  for (; i + 4 <= num; i += 4) {
    int s0 = ebuf[beg + i + 0];
    int s1 = ebuf[beg + i + 1];
    int s2 = ebuf[beg + i + 2];
    int s3 = ebuf[beg + i + 3];
    float w0 = norm[s0], w1 = norm[s1], w2 = norm[s2], w3 = norm[s3];
    const float* r0 = (s0 < NU) ? ue + (size_t)s0 * DD : ie + (size_t)(s0 - NU) * DD;
    const float* r1 = (s1 < NU) ? ue + (size_t)s1 * DD : ie + (size_t)(s1 - NU) * DD;
    const float* r2 = (s2 < NU) ? ue + (size_t)s2 * DD : ie + (size_t)(s2 - NU) * DD;
    const float* r3 = (s3 < NU) ? ue + (size_t)s3 * DD : ie + (size_t)(s3 - NU) * DD;
    a0 = fmaf(w0, r0[lane], a0);
    a1 = fmaf(w1, r1[lane], a1);
    a2 = fmaf(w2, r2[lane], a2);
    a3 = fmaf(w3, r3[lane], a3);
  }
  for (; i < num; ++i) {
    int s0 = ebuf[beg + i];
    float w0 = norm[s0];
    const float* r0 = (s0 < NU) ? ue + (size_t)s0 * DD : ie + (size_t)(s0 - NU) * DD;
    a0 = fmaf(w0, r0[lane], a0);
  }
  g[(size_t)d * DD + lane] = (a0 + a1) + (a2 + a3);
}

__launch_bounds__(256)
__global__ void node_mfma_kernel(const float* __restrict__ ue,
                                 const float* __restrict__ ie,
                                 const float* __restrict__ norm,
                                 const float* __restrict__ W1,
                                 const float* __restrict__ W2,
                                 const float* __restrict__ g,
                                 float* __restrict__ out,
                                 int Nn, int NU) {
  int lane = threadIdx.x & 63;
  int l15 = lane & 15;
  int lg  = lane >> 4;
  int tile = blockIdx.x * 4 + (threadIdx.x >> 6);

  bfrag w1f[2][4], w2f[2][4];
#pragma unroll
  for (int jt = 0; jt < 4; ++jt) {
    int wrow = jt * 16 + l15;
#pragma unroll
    for (int ks = 0; ks < 2; ++ks) {
      int kb = ks * 32 + lg * 8;
      const float* p1 = W1 + wrow * DD + kb;
      const float* p2 = W2 + wrow * DD + kb;
#pragma unroll
      for (int j = 0; j < 8; ++j) {
        w1f[ks][jt][j] = f2bf(p1[j]);
        w2f[ks][jt][j] = f2bf(p2[j]);
      }
    }
  }

  if (tile * 16 >= Nn) return;
  int node = tile * 16 + l15;
  int nclamp = (node < Nn) ? node : (Nn - 1);
  const float* hrow = (nclamp < NU) ? ue + (size_t)nclamp * DD
                                    : ie + (size_t)(nclamp - NU) * DD;
  const float* grow = g + (size_t)nclamp * DD;
  float nd = norm[nclamp];

  ffrag acc[4];
#pragma unroll
  for (int jt = 0; jt < 4; ++jt) acc[jt] = (ffrag){0.f, 0.f, 0.f, 0.f};

#pragma unroll
  for (int ks = 0; ks < 2; ++ks) {
    int kb = ks * 32 + lg * 8;
    bfrag xf, yf;
#pragma unroll
    for (int j = 0; j < 8; ++j) {
      float gv = grow[kb + j];
      float hv = hrow[kb + j];
      xf[j] = f2bf(fmaf(nd, gv, hv));
      yf[j] = f2bf(nd * gv * hv);
    }
#pragma unroll
    for (int jt = 0; jt < 4; ++jt) {
      acc[jt] = __builtin_amdgcn_mfma_f32_16x16x32_bf16(xf, w1f[ks][jt], acc[jt], 0, 0, 0);
      acc[jt] = __builtin_amdgcn_mfma_f32_16x16x32_bf16(yf, w2f[ks][jt], acc[jt], 0, 0, 0);
    }
  }

  float v[4][4];
  float ss[4];
#pragma unroll
  for (int r = 0; r < 4; ++r) {
    float s = 0.f;
#pragma unroll
    for (int jt = 0; jt < 4; ++jt) {
      float m = acc[jt][r];
      float t = (m >= 0.f) ? m : 0.2f * m;
      v[r][jt] = t;
      s = fmaf(t, t, s);
    }
#pragma unroll
    for (int off = 1; off < 16; off <<= 1) s += __shfl_xor(s, off);
    ss[r] = s;
  }
#pragma unroll
  for (int r = 0; r < 4; ++r) {
    int orow = tile * 16 + lg * 4 + r;
    if (orow < Nn) {
      float inv = 1.0f / fmaxf(sqrtf(ss[r]), 1e-12f);
#pragma unroll
      for (int jt = 0; jt < 4; ++jt)
        out[(size_t)orow * DD + jt * 16 + l15] = v[r][jt] * inv;
    }
  }
}

// =====================  launch  =====================

extern "C" void kernel_launch(void* const* d_in, const int* in_sizes, int n_in,
                              void* d_out, int out_size, void* d_ws, size_t ws_size,
                              hipStream_t stream) {
  const float* ue   = (const float*)d_in[0];
  const float* ie   = (const float*)d_in[1];
  const float* norm = (const float*)d_in[2];
  const int*   src  = (const int*)d_in[3];
  const int*   dst  = (const int*)d_in[4];
  const float* W1   = (const float*)d_in[5];
  const float* W2   = (const float*)d_in[6];
  float* out = (float*)d_out;

  int NU = in_sizes[0] / DD;
  int Nn = in_sizes[2];
  int E  = in_sizes[3];

  int NB = (Nn + 255) >> 8;

  size_t un = ((size_t)E > (size_t)Nn * 32) ? (size_t)E : (size_t)Nn * 32;
  size_t new_ints = 1538 + 2 * (size_t)Nn + (size_t)E + un + 4;
  size_t new_bytes = new_ints * sizeof(int);

  size_t csr_ints = (size_t)3 * Nn + 64 + (size_t)E;
  size_t csr_bytes = csr_ints * sizeof(int);

  if (NB <= 512 && ws_size >= new_bytes) {
    int* ccnt    = (int*)d_ws;          // 512
    int* cbase   = ccnt + 512;          // 513
    int* ccursor = cbase + 513;         // 512  (1537 total, pad to 1538)
    int* offs    = ccnt + 1538;
    int* cnt     = offs + Nn;
    int* ebuf    = cnt + Nn;
    uintptr_t up = (uintptr_t)(ebuf + E);
    up = (up + 7) & ~(uintptr_t)7;
    unsigned*       pairb = (unsigned*)up;
    unsigned short* hsc   = (unsigned short*)up;   // aliases pairb (dead after fine)

    hipMemsetAsync(ccnt, 0, 512 * sizeof(int), stream);

    int EB = (E + 4095) / 4096;
    chist_kernel<<<EB, 256, 0, stream>>>(dst, ccnt, E, NB);
    cscan_kernel<<<1, 256, 0, stream>>>(ccnt, cbase, ccursor, NB);
    cscatter_kernel<<<EB, 256, 0, stream>>>(src, dst, ccursor, pairb, E, NB);
    fine_kernel<<<NB, 256, 0, stream>>>(pairb, cbase, offs, cnt, ebuf, Nn);
    hconv_kernel<<<(Nn * 16 + 255) / 256, 256, 0, stream>>>(ue, ie, norm, hsc, Nn, NU);

    int ntiles = (Nn + 15) / 16;
    tile_fused_kernel<<<ntiles, 256, 0, stream>>>(hsc, norm, W1, W2,
                                                  offs, cnt, ebuf, out, Nn);
  } else if (ws_size >= csr_bytes) {
    int* cnt    = (int*)d_ws;
    int* offs   = cnt + Nn;
    int* cursor = offs + Nn;
    int* bsum   = cursor + Nn;
    int* ebuf   = bsum + 64;
    size_t g_bytes = (size_t)Nn * DD * sizeof(float);
    float* g = (ws_size >= csr_bytes + g_bytes) ? (float*)(ebuf + E) : out;

    hipMemsetAsync(cnt, 0, (size_t)Nn * sizeof(int), stream);
    int eblk = (E + 255) / 256;
    hist_kernel<<<eblk, 256, 0, stream>>>(dst, cnt, E);
    int nblkA = (Nn + 4095) / 4096;
    scanA_kernel<<<nblkA, 256, 0, stream>>>(cnt, offs, bsum, Nn);
    scanB_kernel<<<1, 64, 0, stream>>>(bsum, nblkA);
    scanC_kernel<<<(Nn + 255) / 256, 256, 0, stream>>>(offs, cursor, bsum, Nn);
    bucket_kernel<<<eblk, 256, 0, stream>>>(src, dst, cursor, ebuf, E);
    gather_g_kernel<<<(Nn + 3) / 4, 256, 0, stream>>>(ue, ie, norm, offs, cnt, ebuf,
                                                      g, Nn, NU);
    int ntiles = (Nn + 15) / 16;
    node_mfma_kernel<<<(ntiles + 3) / 4, 256, 0, stream>>>(ue, ie, norm, W1, W2, g, out,
                                                           Nn, NU);
  }
}

// Round 11
// 149.937 us; speedup vs baseline: 4.8693x; 1.6832x over previous
//
#include <hip/hip_runtime.h>

#define DD 64

typedef __attribute__((ext_vector_type(8))) short bfrag;
typedef __attribute__((ext_vector_type(4))) float ffrag;

static __device__ __forceinline__ short f2bf(float f) {
  union { float f; unsigned u; } v; v.f = f;
  unsigned r = v.u + 0x7fff + ((v.u >> 16) & 1);  // RNE
  return (short)(r >> 16);
}
static __device__ __forceinline__ float bf2f(unsigned short u) {
  union { unsigned u; float f; } v; v.u = ((unsigned)u) << 16; return v.f;
}

// ================== two-level CSR build (coarse 256-node buckets) ==================

__global__ void chist_kernel(const int* __restrict__ dst, int* __restrict__ ccnt,
                             int E, int NB) {
  __shared__ int ch[512];
  for (int i = threadIdx.x; i < 512; i += 256) ch[i] = 0;
  __syncthreads();
  int ebase = blockIdx.x * 4096;
#pragma unroll
  for (int j = 0; j < 16; ++j) {
    int e = ebase + j * 256 + threadIdx.x;
    if (e < E) atomicAdd(&ch[dst[e] >> 8], 1);
  }
  __syncthreads();
  for (int b = threadIdx.x; b < NB; b += 256) {
    int c = ch[b];
    if (c) atomicAdd(&ccnt[b], c);
  }
}

__global__ void cscan_kernel(const int* __restrict__ ccnt, int* __restrict__ cbase,
                             int* __restrict__ ccursor, int NB) {
  __shared__ int wtot[4];
  int t = threadIdx.x;
  int i0 = t * 2, i1 = t * 2 + 1;
  int v0 = (i0 < NB) ? ccnt[i0] : 0;
  int v1 = (i1 < NB) ? ccnt[i1] : 0;
  int s = v0 + v1;
  int lane = t & 63, w = t >> 6;
  int ps = s;
#pragma unroll
  for (int off = 1; off < 64; off <<= 1) {
    int tmp = __shfl_up(ps, off);
    if (lane >= off) ps += tmp;
  }
  if (lane == 63) wtot[w] = ps;
  __syncthreads();
  int wbase = 0;
  for (int k = 0; k < w; ++k) wbase += wtot[k];
  int excl = wbase + ps - s;
  if (i0 < NB) { cbase[i0] = excl;      ccursor[i0] = excl; }
  if (i1 < NB) { cbase[i1] = excl + v0; ccursor[i1] = excl + v0; }
  if (t == 0) {
    int tot = 0;
    for (int k = 0; k < 4; ++k) tot += wtot[k];
    cbase[NB] = tot;
  }
}

__global__ void cscatter_kernel(const int* __restrict__ src, const int* __restrict__ dst,
                                int* __restrict__ ccursor, unsigned* __restrict__ pairb,
                                int E, int NB) {
  __shared__ int bh[512], bbase[512], brank[512];
  for (int i = threadIdx.x; i < 512; i += 256) { bh[i] = 0; brank[i] = 0; }
  __syncthreads();
  int ebase = blockIdx.x * 4096;
  int se[16], de[16];
#pragma unroll
  for (int j = 0; j < 16; ++j) {
    int e = ebase + j * 256 + threadIdx.x;
    if (e < E) {
      se[j] = src[e];
      de[j] = dst[e];
      atomicAdd(&bh[de[j] >> 8], 1);
    } else {
      se[j] = -1; de[j] = 0;
    }
  }
  __syncthreads();
  for (int b = threadIdx.x; b < NB; b += 256) {
    int c = bh[b];
    bbase[b] = c ? atomicAdd(&ccursor[b], c) : 0;
  }
  __syncthreads();
#pragma unroll
  for (int j = 0; j < 16; ++j) {
    if (se[j] >= 0) {
      int b = de[j] >> 8;
      int r = atomicAdd(&brank[b], 1);
      pairb[bbase[b] + r] = ((unsigned)se[j] << 8) | (unsigned)(de[j] & 255);
    }
  }
}

__global__ void fine_kernel(const unsigned* __restrict__ pairb,
                            const int* __restrict__ cbase,
                            int* __restrict__ offs, int* __restrict__ cnt,
                            int* __restrict__ ebuf, int Nn) {
  __shared__ int fh[256], fcur[256];
  __shared__ int wtot[4];
  int t = threadIdx.x, b = blockIdx.x;
  int nb0 = b << 8;
  int cbeg = cbase[b], cend = cbase[b + 1];
  fh[t] = 0;
  __syncthreads();
  for (int p = cbeg + t; p < cend; p += 256) atomicAdd(&fh[pairb[p] & 255u], 1);
  __syncthreads();
  int val = fh[t];
  int lane = t & 63, w = t >> 6;
  int ps = val;
#pragma unroll
  for (int off = 1; off < 64; off <<= 1) {
    int tmp = __shfl_up(ps, off);
    if (lane >= off) ps += tmp;
  }
  if (lane == 63) wtot[w] = ps;
  __syncthreads();
  int wbase = 0;
  for (int k = 0; k < w; ++k) wbase += wtot[k];
  int excl = wbase + ps - val;
  int node = nb0 + t;
  if (node < Nn) { offs[node] = cbeg + excl; cnt[node] = val; }
  fcur[t] = cbeg + excl;
  __syncthreads();
  for (int p = cbeg + t; p < cend; p += 256) {
    unsigned v = pairb[p];
    int pos = atomicAdd(&fcur[v & 255u], 1);
    ebuf[pos] = (int)(v >> 8);
  }
}

// ================== pre-scale h by norm into bf16 ==================

__global__ void hconv_kernel(const float* __restrict__ ue, const float* __restrict__ ie,
                             const float* __restrict__ norm,
                             unsigned short* __restrict__ hsc, int Nn, int NU) {
  int tid = blockIdx.x * blockDim.x + threadIdx.x;
  if (tid >= Nn * 16) return;
  int row = tid >> 4;
  int q = tid & 15;
  const float* hr = (row < NU) ? ue + (size_t)row * DD : ie + (size_t)(row - NU) * DD;
  float nr = norm[row];
  float4 hv = reinterpret_cast<const float4*>(hr)[q];
  unsigned u0 = (unsigned short)f2bf(nr * hv.x);
  unsigned u1 = (unsigned short)f2bf(nr * hv.y);
  unsigned u2 = (unsigned short)f2bf(nr * hv.z);
  unsigned u3 = (unsigned short)f2bf(nr * hv.w);
  uint2 pk;
  pk.x = u0 | (u1 << 16);
  pk.y = u2 | (u3 << 16);
  *reinterpret_cast<uint2*>(hsc + (size_t)row * DD + q * 4) = pk;
}

// ========== gather (R5 shape, 8-deep): g_bf16[d] = sum hsc[s] ==========
__launch_bounds__(256)
__global__ void gather8_kernel(const unsigned short* __restrict__ hsc,
                               const int* __restrict__ offs,
                               const int* __restrict__ cnt,
                               const int* __restrict__ ebuf,
                               unsigned short* __restrict__ g, int Nn) {
  int lane = threadIdx.x & 63;
  int wid = blockIdx.x * 4 + (threadIdx.x >> 6);
  int d = __builtin_amdgcn_readfirstlane(wid);
  if (d >= Nn) return;
  int beg = __builtin_amdgcn_readfirstlane(offs[d]);
  int num = __builtin_amdgcn_readfirstlane(cnt[d]);
  float a0 = 0.f, a1 = 0.f, a2 = 0.f, a3 = 0.f;
  float a4 = 0.f, a5 = 0.f, a6 = 0.f, a7 = 0.f;
  int i = 0;
  for (; i + 8 <= num; i += 8) {
    int s0 = ebuf[beg + i + 0];
    int s1 = ebuf[beg + i + 1];
    int s2 = ebuf[beg + i + 2];
    int s3 = ebuf[beg + i + 3];
    int s4 = ebuf[beg + i + 4];
    int s5 = ebuf[beg + i + 5];
    int s6 = ebuf[beg + i + 6];
    int s7 = ebuf[beg + i + 7];
    a0 += bf2f(hsc[(size_t)s0 * DD + lane]);
    a1 += bf2f(hsc[(size_t)s1 * DD + lane]);
    a2 += bf2f(hsc[(size_t)s2 * DD + lane]);
    a3 += bf2f(hsc[(size_t)s3 * DD + lane]);
    a4 += bf2f(hsc[(size_t)s4 * DD + lane]);
    a5 += bf2f(hsc[(size_t)s5 * DD + lane]);
    a6 += bf2f(hsc[(size_t)s6 * DD + lane]);
    a7 += bf2f(hsc[(size_t)s7 * DD + lane]);
  }
  for (; i + 4 <= num; i += 4) {
    int s0 = ebuf[beg + i + 0];
    int s1 = ebuf[beg + i + 1];
    int s2 = ebuf[beg + i + 2];
    int s3 = ebuf[beg + i + 3];
    a0 += bf2f(hsc[(size_t)s0 * DD + lane]);
    a1 += bf2f(hsc[(size_t)s1 * DD + lane]);
    a2 += bf2f(hsc[(size_t)s2 * DD + lane]);
    a3 += bf2f(hsc[(size_t)s3 * DD + lane]);
  }
  for (; i < num; ++i) a0 += bf2f(hsc[(size_t)ebuf[beg + i] * DD + lane]);
  float r = ((a0 + a1) + (a2 + a3)) + ((a4 + a5) + (a6 + a7));
  g[(size_t)d * DD + lane] = (unsigned short)f2bf(r);
}

// fp32-g variant (g aliases d_out in the fallback)
__launch_bounds__(256)
__global__ void gather8f_kernel(const unsigned short* __restrict__ hsc,
                                const int* __restrict__ offs,
                                const int* __restrict__ cnt,
                                const int* __restrict__ ebuf,
                                float* __restrict__ g, int Nn) {
  int lane = threadIdx.x & 63;
  int wid = blockIdx.x * 4 + (threadIdx.x >> 6);
  int d = __builtin_amdgcn_readfirstlane(wid);
  if (d >= Nn) return;
  int beg = __builtin_amdgcn_readfirstlane(offs[d]);
  int num = __builtin_amdgcn_readfirstlane(cnt[d]);
  float a0 = 0.f, a1 = 0.f, a2 = 0.f, a3 = 0.f;
  float a4 = 0.f, a5 = 0.f, a6 = 0.f, a7 = 0.f;
  int i = 0;
  for (; i + 8 <= num; i += 8) {
    int s0 = ebuf[beg + i + 0];
    int s1 = ebuf[beg + i + 1];
    int s2 = ebuf[beg + i + 2];
    int s3 = ebuf[beg + i + 3];
    int s4 = ebuf[beg + i + 4];
    int s5 = ebuf[beg + i + 5];
    int s6 = ebuf[beg + i + 6];
    int s7 = ebuf[beg + i + 7];
    a0 += bf2f(hsc[(size_t)s0 * DD + lane]);
    a1 += bf2f(hsc[(size_t)s1 * DD + lane]);
    a2 += bf2f(hsc[(size_t)s2 * DD + lane]);
    a3 += bf2f(hsc[(size_t)s3 * DD + lane]);
    a4 += bf2f(hsc[(size_t)s4 * DD + lane]);
    a5 += bf2f(hsc[(size_t)s5 * DD + lane]);
    a6 += bf2f(hsc[(size_t)s6 * DD + lane]);
    a7 += bf2f(hsc[(size_t)s7 * DD + lane]);
  }
  for (; i + 4 <= num; i += 4) {
    int s0 = ebuf[beg + i + 0];
    int s1 = ebuf[beg + i + 1];
    int s2 = ebuf[beg + i + 2];
    int s3 = ebuf[beg + i + 3];
    a0 += bf2f(hsc[(size_t)s0 * DD + lane]);
    a1 += bf2f(hsc[(size_t)s1 * DD + lane]);
    a2 += bf2f(hsc[(size_t)s2 * DD + lane]);
    a3 += bf2f(hsc[(size_t)s3 * DD + lane]);
  }
  for (; i < num; ++i) a0 += bf2f(hsc[(size_t)ebuf[beg + i] * DD + lane]);
  g[(size_t)d * DD + lane] = ((a0 + a1) + (a2 + a3)) + ((a4 + a5) + (a6 + a7));
}

// ============ node MFMA from hsc + bf16 g, fused LReLU + L2-normalize ============
// x = nd*g + hsc/nd ; y = g .* hsc   (hsc = nd*h)
__launch_bounds__(256)
__global__ void node_hsc_kernel(const unsigned short* __restrict__ hsc,
                                const unsigned short* __restrict__ g,
                                const float* __restrict__ norm,
                                const float* __restrict__ W1,
                                const float* __restrict__ W2,
                                float* __restrict__ out, int Nn) {
  int lane = threadIdx.x & 63;
  int l15 = lane & 15;
  int lg  = lane >> 4;
  int tile = blockIdx.x * 4 + (threadIdx.x >> 6);

  bfrag w1f[2][4], w2f[2][4];
#pragma unroll
  for (int jt = 0; jt < 4; ++jt) {
    int wrow = jt * 16 + l15;
#pragma unroll
    for (int ks = 0; ks < 2; ++ks) {
      int kb = ks * 32 + lg * 8;
      const float* p1 = W1 + wrow * DD + kb;
      const float* p2 = W2 + wrow * DD + kb;
#pragma unroll
      for (int j = 0; j < 8; ++j) {
        w1f[ks][jt][j] = f2bf(p1[j]);
        w2f[ks][jt][j] = f2bf(p2[j]);
      }
    }
  }

  if (tile * 16 >= Nn) return;
  int node = tile * 16 + l15;
  int nc = (node < Nn) ? node : (Nn - 1);
  float nd = norm[nc];
  float rnd = 1.0f / nd;

  ffrag acc[4];
#pragma unroll
  for (int jt = 0; jt < 4; ++jt) acc[jt] = (ffrag){0.f, 0.f, 0.f, 0.f};

#pragma unroll
  for (int ks = 0; ks < 2; ++ks) {
    int kb = ks * 32 + lg * 8;
    bfrag gb = *reinterpret_cast<const bfrag*>(g + (size_t)nc * DD + kb);
    bfrag hb = *reinterpret_cast<const bfrag*>(hsc + (size_t)nc * DD + kb);
    bfrag xf, yf;
#pragma unroll
    for (int j = 0; j < 8; ++j) {
      float gv = bf2f((unsigned short)gb[j]);
      float hj = bf2f((unsigned short)hb[j]);     // = nd * h_j
      xf[j] = f2bf(fmaf(nd, gv, hj * rnd));       // nd*g + h
      yf[j] = f2bf(gv * hj);                      // nd*(g.*h)
    }
#pragma unroll
    for (int jt = 0; jt < 4; ++jt) {
      acc[jt] = __builtin_amdgcn_mfma_f32_16x16x32_bf16(xf, w1f[ks][jt], acc[jt], 0, 0, 0);
      acc[jt] = __builtin_amdgcn_mfma_f32_16x16x32_bf16(yf, w2f[ks][jt], acc[jt], 0, 0, 0);
    }
  }

  float v[4][4];
  float ss[4];
#pragma unroll
  for (int r = 0; r < 4; ++r) {
    float s = 0.f;
#pragma unroll
    for (int jt = 0; jt < 4; ++jt) {
      float m = acc[jt][r];
      float t = (m >= 0.f) ? m : 0.2f * m;
      v[r][jt] = t;
      s = fmaf(t, t, s);
    }
#pragma unroll
    for (int off = 1; off < 16; off <<= 1) s += __shfl_xor(s, off);
    ss[r] = s;
  }
#pragma unroll
  for (int r = 0; r < 4; ++r) {
    int orow = tile * 16 + lg * 4 + r;
    if (orow < Nn) {
      float inv = 1.0f / fmaxf(sqrtf(ss[r]), 1e-12f);
#pragma unroll
      for (int jt = 0; jt < 4; ++jt)
        out[(size_t)orow * DD + jt * 16 + l15] = v[r][jt] * inv;
    }
  }
}

// fp32-g variant (g aliases d_out; wave reads its tile's g rows before storing)
__launch_bounds__(256)
__global__ void node_hscf_kernel(const unsigned short* __restrict__ hsc,
                                 const float* __restrict__ g,
                                 const float* __restrict__ norm,
                                 const float* __restrict__ W1,
                                 const float* __restrict__ W2,
                                 float* __restrict__ out, int Nn) {
  int lane = threadIdx.x & 63;
  int l15 = lane & 15;
  int lg  = lane >> 4;
  int tile = blockIdx.x * 4 + (threadIdx.x >> 6);

  bfrag w1f[2][4], w2f[2][4];
#pragma unroll
  for (int jt = 0; jt < 4; ++jt) {
    int wrow = jt * 16 + l15;
#pragma unroll
    for (int ks = 0; ks < 2; ++ks) {
      int kb = ks * 32 + lg * 8;
      const float* p1 = W1 + wrow * DD + kb;
      const float* p2 = W2 + wrow * DD + kb;
#pragma unroll
      for (int j = 0; j < 8; ++j) {
        w1f[ks][jt][j] = f2bf(p1[j]);
        w2f[ks][jt][j] = f2bf(p2[j]);
      }
    }
  }

  if (tile * 16 >= Nn) return;
  int node = tile * 16 + l15;
  int nc = (node < Nn) ? node : (Nn - 1);
  float nd = norm[nc];
  float rnd = 1.0f / nd;

  ffrag acc[4];
#pragma unroll
  for (int jt = 0; jt < 4; ++jt) acc[jt] = (ffrag){0.f, 0.f, 0.f, 0.f};

#pragma unroll
  for (int ks = 0; ks < 2; ++ks) {
    int kb = ks * 32 + lg * 8;
    float4 g0 = *reinterpret_cast<const float4*>(g + (size_t)nc * DD + kb);
    float4 g1 = *reinterpret_cast<const float4*>(g + (size_t)nc * DD + kb + 4);
    bfrag hb = *reinterpret_cast<const bfrag*>(hsc + (size_t)nc * DD + kb);
    float gv[8] = {g0.x, g0.y, g0.z, g0.w, g1.x, g1.y, g1.z, g1.w};
    bfrag xf, yf;
#pragma unroll
    for (int j = 0; j < 8; ++j) {
      float hj = bf2f((unsigned short)hb[j]);
      xf[j] = f2bf(fmaf(nd, gv[j], hj * rnd));
      yf[j] = f2bf(gv[j] * hj);
    }
#pragma unroll
    for (int jt = 0; jt < 4; ++jt) {
      acc[jt] = __builtin_amdgcn_mfma_f32_16x16x32_bf16(xf, w1f[ks][jt], acc[jt], 0, 0, 0);
      acc[jt] = __builtin_amdgcn_mfma_f32_16x16x32_bf16(yf, w2f[ks][jt], acc[jt], 0, 0, 0);
    }
  }

  float v[4][4];
  float ss[4];
#pragma unroll
  for (int r = 0; r < 4; ++r) {
    float s = 0.f;
#pragma unroll
    for (int jt = 0; jt < 4; ++jt) {
      float m = acc[jt][r];
      float t = (m >= 0.f) ? m : 0.2f * m;
      v[r][jt] = t;
      s = fmaf(t, t, s);
    }
#pragma unroll
    for (int off = 1; off < 16; off <<= 1) s += __shfl_xor(s, off);
    ss[r] = s;
  }
#pragma unroll
  for (int r = 0; r < 4; ++r) {
    int orow = tile * 16 + lg * 4 + r;
    if (orow < Nn) {
      float inv = 1.0f / fmaxf(sqrtf(ss[r]), 1e-12f);
#pragma unroll
      for (int jt = 0; jt < 4; ++jt)
        out[(size_t)orow * DD + jt * 16 + l15] = v[r][jt] * inv;
    }
  }
}

// =====================  launch  =====================

extern "C" void kernel_launch(void* const* d_in, const int* in_sizes, int n_in,
                              void* d_out, int out_size, void* d_ws, size_t ws_size,
                              hipStream_t stream) {
  const float* ue   = (const float*)d_in[0];
  const float* ie   = (const float*)d_in[1];
  const float* norm = (const float*)d_in[2];
  const int*   src  = (const int*)d_in[3];
  const int*   dst  = (const int*)d_in[4];
  const float* W1   = (const float*)d_in[5];
  const float* W2   = (const float*)d_in[6];
  float* out = (float*)d_out;

  int NU = in_sizes[0] / DD;
  int Nn = in_sizes[2];
  int E  = in_sizes[3];

  int NB = (Nn + 255) >> 8;
  if (NB > 512) return;  // problem size fixed; guard only

  // hsc needs Nn*64 ushorts = Nn*32 ints. pairb needs E ints. They share a union
  // (pairb dead after fine_kernel). g (bf16, Nn*64 ushorts = Nn*32 ints) is a
  // separate region AFTER the union.
  size_t un      = ((size_t)E > (size_t)Nn * 32) ? (size_t)E : (size_t)Nn * 32;
  size_t base_ints = 1538 + 2 * (size_t)Nn + (size_t)E + un + 16;
  size_t g_ints    = (size_t)Nn * 32;
  size_t ext_ints  = base_ints + g_ints + 16;

  int* ccnt    = (int*)d_ws;          // 512
  int* cbase   = ccnt + 512;          // 513
  int* ccursor = cbase + 513;         // 512  (1537 total, pad to 1538)
  int* offs    = ccnt + 1538;
  int* cnt     = offs + Nn;
  int* ebuf    = cnt + Nn;
  uintptr_t up = (uintptr_t)(ebuf + E);
  up = (up + 15) & ~(uintptr_t)15;
  unsigned*       pairb = (unsigned*)up;
  unsigned short* hsc   = (unsigned short*)up;   // aliases pairb (dead after fine)

  hipMemsetAsync(ccnt, 0, 512 * sizeof(int), stream);

  int EB = (E + 4095) / 4096;
  chist_kernel<<<EB, 256, 0, stream>>>(dst, ccnt, E, NB);
  cscan_kernel<<<1, 256, 0, stream>>>(ccnt, cbase, ccursor, NB);
  cscatter_kernel<<<EB, 256, 0, stream>>>(src, dst, ccursor, pairb, E, NB);
  fine_kernel<<<NB, 256, 0, stream>>>(pairb, cbase, offs, cnt, ebuf, Nn);
  hconv_kernel<<<(Nn * 16 + 255) / 256, 256, 0, stream>>>(ue, ie, norm, hsc, Nn, NU);

  int gblk = (Nn + 3) / 4;
  int ntiles = (Nn + 15) / 16;
  int nblk = (ntiles + 3) / 4;

  if (ws_size >= ext_ints * sizeof(int)) {
    // bf16 g in workspace, after the full union region (hsc tail is un ints wide)
    uintptr_t gp = up + un * sizeof(int);
    gp = (gp + 15) & ~(uintptr_t)15;
    unsigned short* gbuf = (unsigned short*)gp;
    gather8_kernel<<<gblk, 256, 0, stream>>>(hsc, offs, cnt, ebuf, gbuf, Nn);
    node_hsc_kernel<<<nblk, 256, 0, stream>>>(hsc, gbuf, norm, W1, W2, out, Nn);
  } else {
    // fp32 g aliases d_out (safe: each wave reads its own tile's g rows, then
    // stores those same rows; no cross-wave overlap)
    gather8f_kernel<<<gblk, 256, 0, stream>>>(hsc, offs, cnt, ebuf, out, Nn);
    node_hscf_kernel<<<nblk, 256, 0, stream>>>(hsc, out, norm, W1, W2, out, Nn);
  }
}